// Round 2
// baseline (350.775 us; speedup 1.0000x reference)
//
#include <hip/hip_runtime.h>
#include <hip/hip_bf16.h>

typedef short s8v __attribute__((ext_vector_type(8)));
typedef float f4v __attribute__((ext_vector_type(4)));

#define MFMA_BF16 __builtin_amdgcn_mfma_f32_16x16x32_bf16

// LDS element offsets (16-bit elements). All 16B-aligned (multiple of 8 el).
constexpr int OFF_W0T  = 0;      // [64][40]  Ws0^T, k<32
constexpr int OFF_W1T  = 2560;   // [64][72]  Ws1^T
constexpr int OFF_W2T  = 7168;   // [16][72]  Ws2^T
constexpr int OFF_WC0T = 8320;   // [64][72]  Wc0^T, zero-padded k in [47,64)
constexpr int OFF_WC1T = 12928;  // [64][72]
constexpr int OFF_WC2T = 17536;  // [64][72]
constexpr int OFF_WC3T = 22144;  // [16][72]  zero rows n>=3
constexpr int OFF_H    = 23296;  // 4 waves x [32 rows][stride 72]
constexpr int SMEM_EL  = 32512;  // 65024 B -> 2 blocks/CU

static __device__ __forceinline__ short bf2s(__hip_bfloat16 h) {
    union { __hip_bfloat16 b; short s; } u; u.b = h; return u.s;
}

__global__ __launch_bounds__(256, 2)
void rf_fused(const void* __restrict__ xv,
              const void* __restrict__ dv,
              const void* __restrict__ Ws0,
              const void* __restrict__ Ws1,
              const void* __restrict__ Ws2,
              const void* __restrict__ Wc0,
              const void* __restrict__ Wc1,
              const void* __restrict__ Wc2,
              const void* __restrict__ Wc3,
              void* __restrict__ outp,
              int npts)
{
    __shared__ __align__(16) short smem[SMEM_EL];
    __shared__ int cls_cnt;
    const int t = threadIdx.x;

    // ---- input dtype self-detection ----
    // bf16 normals: biased exponent ~[110,140] essentially always.
    // fp32-viewed-as-u16: even words are low mantissa bits -> ~12% in range.
    if (t == 0) cls_cnt = 0;
    __syncthreads();
    {
        unsigned short w = ((const unsigned short*)xv)[2 * t];
        int e = (w >> 7) & 0xFF;
        if (e >= 110 && e <= 140) atomicAdd(&cls_cnt, 1);
    }
    __syncthreads();
    const bool isbf = (cls_cnt >= 128);

    // load a weight element as bf16 bits, from either dtype
    auto ldw = [&](const void* p, int idx) -> short {
        if (isbf) return ((const short*)p)[idx];
        return bf2s(__float2bfloat16(((const float*)p)[idx]));
    };

    // ---- stage weights transposed: sW[n][k] = W[k][n] ----
    for (int i = t; i < 2048; i += 256) { int k = i >> 6, n = i & 63; smem[OFF_W0T  + n*40 + k] = ldw(Ws0, i); }
    for (int i = t; i < 4096; i += 256) { int k = i >> 6, n = i & 63; smem[OFF_W1T  + n*72 + k] = ldw(Ws1, i); }
    for (int i = t; i < 1024; i += 256) { int k = i >> 4, n = i & 15; smem[OFF_W2T  + n*72 + k] = ldw(Ws2, i); }
    for (int i = t; i < 4096; i += 256) { int n = i >> 6, k = i & 63; smem[OFF_WC0T + n*72 + k] = (k < 47) ? ldw(Wc0, k*64 + n) : (short)0; }
    for (int i = t; i < 4096; i += 256) { int k = i >> 6, n = i & 63; smem[OFF_WC1T + n*72 + k] = ldw(Wc1, i); }
    for (int i = t; i < 4096; i += 256) { int k = i >> 6, n = i & 63; smem[OFF_WC2T + n*72 + k] = ldw(Wc2, i); }
    for (int i = t; i < 1024; i += 256) { int n = i >> 6, k = i & 63; smem[OFF_WC3T + n*72 + k] = (n < 3) ? ldw(Wc3, k*3 + n) : (short)0; }
    __syncthreads();

    const int lane = t & 63;
    const int wv   = t >> 6;
    const int m16  = lane & 15;   // A-row / B-col / D-col within a 16-tile
    const int q    = lane >> 4;   // quad: A/B k-group, D row-group
    short* sH = smem + OFF_H + wv * 2304;  // per-wave [32][72]

    const f4v zf = {0.f, 0.f, 0.f, 0.f};

    // 8 contiguous elements of a 32-wide row from x/d, as bf16 bits
    auto loadRow8 = [&](const void* p, int eoff) -> s8v {
        s8v r;
        if (isbf) {
            r = *(const s8v*)((const short*)p + eoff);
        } else {
            const float* f = (const float*)p + eoff;
            f4v f0 = *(const f4v*)f;
            f4v f1 = *(const f4v*)(f + 4);
            #pragma unroll
            for (int j = 0; j < 4; j++) {
                r[j]     = bf2s(__float2bfloat16(f0[j]));
                r[j + 4] = bf2s(__float2bfloat16(f1[j]));
            }
        }
        return r;
    };
    auto putOut = [&](int idx, float v) {
        if (isbf) ((short*)outp)[idx] = bf2s(__float2bfloat16(v));
        else      ((float*)outp)[idx] = v;
    };

    // A-frag loads from sH: A[m=m16][k=ks*32+q*8+j]
    auto loadAH = [&](s8v (&af)[2][2]) {
        asm volatile("" ::: "memory");   // fence vs preceding H stores
        #pragma unroll
        for (int mt = 0; mt < 2; mt++)
            #pragma unroll
            for (int ks = 0; ks < 2; ks++)
                af[mt][ks] = *(const s8v*)(sH + (mt*16 + m16)*72 + ks*32 + q*8);
    };
    // 64-wide layer: acc[mt][nt] = A(32x64) @ W(64x64)
    auto layer64 = [&](int woff, f4v (&a)[2][4], const s8v (&af)[2][2]) {
        #pragma unroll
        for (int nt = 0; nt < 4; nt++) {
            s8v b0 = *(const s8v*)(smem + woff + (nt*16 + m16)*72 + q*8);
            s8v b1 = *(const s8v*)(smem + woff + (nt*16 + m16)*72 + 32 + q*8);
            #pragma unroll
            for (int mt = 0; mt < 2; mt++)
                a[mt][nt] = MFMA_BF16(af[mt][1], b1, MFMA_BF16(af[mt][0], b0, zf, 0,0,0), 0,0,0);
        }
    };
    // relu + write 32x64 D tiles to sH (D: row = q*4+r, col = m16, per 16-tile)
    auto storeH64 = [&](const f4v (&a)[2][4]) {
        #pragma unroll
        for (int mt = 0; mt < 2; mt++)
            #pragma unroll
            for (int nt = 0; nt < 4; nt++)
                #pragma unroll
                for (int r = 0; r < 4; r++)
                    sH[(mt*16 + q*4 + r)*72 + nt*16 + m16] =
                        bf2s(__float2bfloat16(fmaxf(a[mt][nt][r], 0.f)));
        asm volatile("" ::: "memory");
    };

    const int ntiles = npts / 32;
    const int nwaves = gridDim.x * 4;
    for (int tile = blockIdx.x*4 + wv; tile < ntiles; tile += nwaves) {
        const int r0 = tile * 32;
        f4v acc[2][4];

        // ---------------- sigma net ----------------
        // L1: X(32x32) @ Ws0(32x64)
        s8v xa[2];
        #pragma unroll
        for (int mt = 0; mt < 2; mt++)
            xa[mt] = loadRow8(xv, (r0 + mt*16 + m16)*32 + q*8);
        #pragma unroll
        for (int nt = 0; nt < 4; nt++) {
            s8v b = *(const s8v*)(smem + OFF_W0T + (nt*16 + m16)*40 + q*8);
            #pragma unroll
            for (int mt = 0; mt < 2; mt++)
                acc[mt][nt] = MFMA_BF16(xa[mt], b, zf, 0,0,0);
        }
        storeH64(acc);   // H1

        // L2: H1 @ Ws1
        s8v a2[2][2];
        loadAH(a2);
        layer64(OFF_W1T, acc, a2);
        storeH64(acc);   // H2

        // L3: H2 @ Ws2 (64x16), one n-tile
        s8v a3[2][2];
        loadAH(a3);
        s8v c0 = *(const s8v*)(smem + OFF_W2T + m16*72 + q*8);
        s8v c1 = *(const s8v*)(smem + OFF_W2T + m16*72 + 32 + q*8);
        f4v acc3[2];
        #pragma unroll
        for (int mt = 0; mt < 2; mt++)
            acc3[mt] = MFMA_BF16(a3[mt][1], c1, MFMA_BF16(a3[mt][0], c0, zf, 0,0,0), 0,0,0);

        // sigma out (col 0) + geo (cols 1..15 -> sH cols 0..14, col 15 zeroed)
        #pragma unroll
        for (int mt = 0; mt < 2; mt++)
            #pragma unroll
            for (int r = 0; r < 4; r++) {
                float v = fmaxf(acc3[mt][r], 0.f);
                int row = mt*16 + q*4 + r;
                if (m16 == 0) {
                    putOut(3*npts + r0 + row, v);
                    sH[row*72 + 15] = 0;
                } else {
                    sH[row*72 + (m16 - 1)] = bf2s(__float2bfloat16(v));
                }
            }
        asm volatile("" ::: "memory");

        // ---------------- color net ----------------
        // Hc0: [d | geo] K=64: k<32 = d, k in [32,47) = geo, k>=47 hits zero
        // weight rows (stale finite sH cols 16..31 contribute exactly 0)
        s8v da[2], ga[2];
        #pragma unroll
        for (int mt = 0; mt < 2; mt++) {
            da[mt] = loadRow8(dv, (r0 + mt*16 + m16)*32 + q*8);
            ga[mt] = *(const s8v*)(sH + (mt*16 + m16)*72 + q*8);
        }
        #pragma unroll
        for (int nt = 0; nt < 4; nt++) {
            s8v b0 = *(const s8v*)(smem + OFF_WC0T + (nt*16 + m16)*72 + q*8);
            s8v b1 = *(const s8v*)(smem + OFF_WC0T + (nt*16 + m16)*72 + 32 + q*8);
            #pragma unroll
            for (int mt = 0; mt < 2; mt++)
                acc[mt][nt] = MFMA_BF16(ga[mt], b1, MFMA_BF16(da[mt], b0, zf, 0,0,0), 0,0,0);
        }
        storeH64(acc);   // H4

        // Wc1
        s8v a5[2][2];
        loadAH(a5);
        layer64(OFF_WC1T, acc, a5);
        storeH64(acc);   // H5

        // Wc2
        s8v a6[2][2];
        loadAH(a6);
        layer64(OFF_WC2T, acc, a6);
        storeH64(acc);   // H6

        // Wc3 (64x3, padded to 16): no relu, sigmoid, write color
        s8v a7[2][2];
        loadAH(a7);
        s8v e0 = *(const s8v*)(smem + OFF_WC3T + m16*72 + q*8);
        s8v e1 = *(const s8v*)(smem + OFF_WC3T + m16*72 + 32 + q*8);
        f4v acc7[2];
        #pragma unroll
        for (int mt = 0; mt < 2; mt++)
            acc7[mt] = MFMA_BF16(a7[mt][1], e1, MFMA_BF16(a7[mt][0], e0, zf, 0,0,0), 0,0,0);

        if (m16 < 3) {
            #pragma unroll
            for (int mt = 0; mt < 2; mt++)
                #pragma unroll
                for (int r = 0; r < 4; r++) {
                    float v  = acc7[mt][r];
                    float sg = 1.0f / (1.0f + __expf(-v));
                    putOut((r0 + mt*16 + q*4 + r)*3 + m16, sg);
                }
        }
    }
}

extern "C" void kernel_launch(void* const* d_in, const int* in_sizes, int n_in,
                              void* d_out, int out_size, void* d_ws, size_t ws_size,
                              hipStream_t stream) {
    const int npts = in_sizes[0] / 32;
    // 512 blocks x 256 thr = 2 blocks/CU resident (LDS-capped)
    rf_fused<<<512, 256, 0, stream>>>(d_in[0], d_in[1], d_in[2], d_in[3], d_in[4],
                                      d_in[5], d_in[6], d_in[7], d_in[8],
                                      d_out, npts);
}